// Round 3
// baseline (2833.713 us; speedup 1.0000x reference)
//
#include <hip/hip_runtime.h>

// Fused: grouped conv3x3x3 (q,k,v) -> per-location attention over depth B=5 ->
// grouped 1x1x1 proj. One thread handles one (batch, head, y, x).
//
// Round-3 structure: uniform-SGPR-base single-instruction loads (per (ic,d)
// plane base is wave-uniform; per-lane voffset spc[dx]; dy tap in the signed
// 13-bit immediate), software-pipelined at plane granularity with a rotating
// 3-buffer and prefetch distance 2, and sched_barrier(0) after each plane's
// FMA block. The barrier bounds the scheduler's live window (~18 tap regs):
// rounds 1-2 showed that without it the scheduler hoists 300+ independent
// loads, blows past the 128-VGPR cap, and spills the q/k/v accumulators
// (2.6-7 GB of scratch traffic, 2.5-3.0 ms).
//
// launch_bounds (256,2): do NOT raise min-waves; (256,4) forces 64 VGPRs and
// catastrophic spill (round-1 post-mortem).

#define WD   128
#define HWs  (128 * 128)
#define BD   5
#define CS   (BD * HWs)   // channel stride = 81920

template<bool EDGE>
__device__ __forceinline__ void tca_body(
    int bi, int hd, int px, int py,
    const float* __restrict__ x, const float* __restrict__ last,
    const float* __restrict__ wq, const float* __restrict__ wk,
    const float* __restrict__ wv, const float* __restrict__ wp,
    float* __restrict__ out)
{
    const int ch0     = hd << 3;                    // input channel base (8 ch)
    const int base_in = (bi * 64 + ch0) * CS;       // uniform

    // ---- per-lane spatial tap offsets ----
    int   spc[3];  float xm[3];
#pragma unroll
    for (int dx = 0; dx < 3; ++dx) {
        const int xx = px + dx - 1;
        const int xc = xx < 0 ? 0 : (xx > 127 ? 127 : xx);
        spc[dx] = py * WD + xc;
        xm[dx]  = ((unsigned)xx < 128u) ? 1.f : 0.f;
    }

    int sp9[9]; float mk9[9];
    if (EDGE) {
#pragma unroll
        for (int dy = 0; dy < 3; ++dy) {
            const int yy  = py + dy - 1;
            const int yc  = yy < 0 ? 0 : (yy > 127 ? 127 : yy);
            const float ym = ((unsigned)yy < 128u) ? 1.f : 0.f;
#pragma unroll
            for (int dx = 0; dx < 3; ++dx) {
                sp9[dy * 3 + dx] = spc[dx] + (yc - py) * WD;
                mk9[dy * 3 + dx] = ym * xm[dx];
            }
        }
    }

    // one (ic,d) plane: 9 taps, single-inst loads off a uniform base
    auto load_plane = [&](const float* __restrict__ bp, float (&t)[9]) {
        if constexpr (EDGE) {
#pragma unroll
            for (int tp = 0; tp < 9; ++tp)
                t[tp] = bp[sp9[tp]] * mk9[tp];
        } else {
#pragma unroll
            for (int dy = 0; dy < 3; ++dy)
#pragma unroll
                for (int dx = 0; dx < 3; ++dx) {
                    float val = bp[spc[dx] + (dy - 1) * WD];  // imm ±512B
                    if (dx != 1) val *= xm[dx];               // x-edge lanes
                    t[dy * 3 + dx] = val;
                }
        }
    };

    float q[4][BD], k[4][BD], v[4][BD];
#pragma unroll
    for (int c = 0; c < 4; ++c)
#pragma unroll
        for (int i = 0; i < BD; ++i) { q[c][i] = 0.f; k[c][i] = 0.f; v[c][i] = 0.f; }

    // ---------- pass 1: q = conv3x3x3(x, wq) ----------
    {
        float tb[3][9];                       // rotating plane buffers
        load_plane(x + base_in + 0 * HWs, tb[0]);   // plane p=0 (ic0,d0)
        load_plane(x + base_in + 1 * HWs, tb[1]);   // plane p=1 (ic0,d1)
#pragma unroll
        for (int p = 0; p < 40; ++p) {
            if (p + 2 < 40) {                 // prefetch distance 2
                const int icn = (p + 2) / 5, dn = (p + 2) % 5;
                load_plane(x + base_in + icn * CS + dn * HWs, tb[(p + 2) % 3]);
            }
            const int ic = p / 5, d = p % 5, c = ic >> 1;
            const float* __restrict__ wr = wq + hd * 216 + ic * 27;
            float (&tc)[9] = tb[p % 3];
#pragma unroll
            for (int dz = 0; dz < 3; ++dz) {
                const int i = d - dz + 1;     // compile-time
                if (0 <= i && i < BD) {
#pragma unroll
                    for (int tp = 0; tp < 9; ++tp)
                        q[c][i] = fmaf(wr[dz * 9 + tp], tc[tp], q[c][i]);
                }
            }
            __builtin_amdgcn_sched_barrier(0);  // bound live window (anti-spill)
        }
    }

    // ---------- pass 2: k,v = conv3x3x3(last, wk/wv) ----------
    {
        float tb[3][9];
        load_plane(last + base_in + 0 * HWs, tb[0]);
        load_plane(last + base_in + 1 * HWs, tb[1]);
#pragma unroll
        for (int p = 0; p < 40; ++p) {
            if (p + 2 < 40) {
                const int icn = (p + 2) / 5, dn = (p + 2) % 5;
                load_plane(last + base_in + icn * CS + dn * HWs, tb[(p + 2) % 3]);
            }
            const int ic = p / 5, d = p % 5, c = ic >> 1;
            const float* __restrict__ wrk = wk + hd * 216 + ic * 27;
            const float* __restrict__ wrv = wv + hd * 216 + ic * 27;
            float (&tc)[9] = tb[p % 3];
#pragma unroll
            for (int dz = 0; dz < 3; ++dz) {
                const int i = d - dz + 1;
                if (0 <= i && i < BD) {
#pragma unroll
                    for (int tp = 0; tp < 9; ++tp) {
                        k[c][i] = fmaf(wrk[dz * 9 + tp], tc[tp], k[c][i]);
                        v[c][i] = fmaf(wrv[dz * 9 + tp], tc[tp], v[c][i]);
                    }
                }
            }
            __builtin_amdgcn_sched_barrier(0);
        }
    }

    // ---------- attention: softmax_j( SCALE * q_i . k_j ) ----------
    const float SCALE = 0.35355339059327373f;   // 8^-0.5
    float p_[BD][BD];
#pragma unroll
    for (int i = 0; i < BD; ++i) {
        float s[BD];
        float m = -3.0e38f;
#pragma unroll
        for (int j = 0; j < BD; ++j) {
            float t = q[0][i] * k[0][j];
            t = fmaf(q[1][i], k[1][j], t);
            t = fmaf(q[2][i], k[2][j], t);
            t = fmaf(q[3][i], k[3][j], t);
            t *= SCALE;
            s[j] = t;
            m = fmaxf(m, t);
        }
        float sum = 0.f;
#pragma unroll
        for (int j = 0; j < BD; ++j) { float e = __expf(s[j] - m); p_[i][j] = e; sum += e; }
        const float r = 1.0f / sum;
#pragma unroll
        for (int j = 0; j < BD; ++j) p_[i][j] *= r;
    }

    // ---------- out = attn @ v, then 1x1 grouped proj, store ----------
    const int sp0 = py * WD + px;
#pragma unroll
    for (int c = 0; c < 4; ++c) {
        const float w0 = wp[ch0 + 2 * c];
        const float w1 = wp[ch0 + 2 * c + 1];
#pragma unroll
        for (int i = 0; i < BD; ++i) {
            float o = p_[i][0] * v[c][0];
            o = fmaf(p_[i][1], v[c][1], o);
            o = fmaf(p_[i][2], v[c][2], o);
            o = fmaf(p_[i][3], v[c][3], o);
            o = fmaf(p_[i][4], v[c][4], o);
            float* __restrict__ ob0 = out + (base_in + (2 * c)     * CS + i * HWs);
            float* __restrict__ ob1 = out + (base_in + (2 * c + 1) * CS + i * HWs);
            ob0[sp0] = w0 * o;
            ob1[sp0] = w1 * o;
        }
    }
}

__global__ __launch_bounds__(256, 2)
void TCA_49177375539279_kernel(const float* __restrict__ x,
                               const float* __restrict__ last,
                               const float* __restrict__ wq,
                               const float* __restrict__ wk,
                               const float* __restrict__ wv,
                               const float* __restrict__ wp,
                               float* __restrict__ out)
{
    const int z  = blockIdx.z;
    const int bi = z >> 3;          // batch 0..7
    const int hd = z & 7;           // head 0..7
    const int px = (blockIdx.x << 6) + (threadIdx.x & 63);   // 0..127 (per-lane)
    // py is wave-uniform -> scalar branch for edge/interior split
    const int py = __builtin_amdgcn_readfirstlane((blockIdx.y << 2) + (threadIdx.x >> 6));

    if (py >= 1 && py <= 126)
        tca_body<false>(bi, hd, px, py, x, last, wq, wk, wv, wp, out);
    else
        tca_body<true >(bi, hd, px, py, x, last, wq, wk, wv, wp, out);
}

extern "C" void kernel_launch(void* const* d_in, const int* in_sizes, int n_in,
                              void* d_out, int out_size, void* d_ws, size_t ws_size,
                              hipStream_t stream)
{
    const float* x    = (const float*)d_in[0];
    const float* last = (const float*)d_in[1];
    const float* wq   = (const float*)d_in[2];
    const float* wk   = (const float*)d_in[3];
    const float* wv   = (const float*)d_in[4];
    const float* wp   = (const float*)d_in[5];
    float* out = (float*)d_out;

    dim3 grid(2, 32, 64);   // (w tiles of 64, h tiles of 4, batch*heads)
    dim3 block(256);
    hipLaunchKernelGGL(TCA_49177375539279_kernel, grid, block, 0, stream,
                       x, last, wq, wk, wv, wp, out);
}

// Round 4
// 740.093 us; speedup vs baseline: 3.8289x; 3.8289x over previous
//
#include <hip/hip_runtime.h>

// Fused: grouped conv3x3x3 (q,k,v) -> per-location attention over depth B=5 ->
// grouped 1x1x1 proj. One thread handles one (batch, head, y, x).
//
// Loop topology is EXACTLY the round-0 skeleton (dy outer loop with
// "#pragma unroll 1", tiny fully-unrollable inner loops, all array indices
// compile-time). Rounds 1-3 post-mortem: any structure relying on LLVM fully
// unrolling a big/complex nest silently fails -> runtime-indexed q/k/v ->
// scratch allocation -> 2-7 GB of spill traffic and 2.5-3 ms. Do not
// restructure into large unrolled pipelines.
//
// Within that skeleton, addressing is upgraded to 1-instruction loads:
//  - py is wave-uniform (readfirstlane) -> row = py+dy-1 is SCALAR; each dy
//    iteration is guarded by a uniform branch (OOB rows contribute zero by
//    conv zero-padding, so skipping them is exact).
//  - inside the guard, base_dy = x + base_in + row*WD is uniform -> SGPR
//    base (+ SALU const per (ic,d) plane); per-lane voffset xc[dx] in
//    [0,127] (clamped, provably non-negative -> saddr form).
//  - x-edge: clamped column + 0/1 mask multiply on the dx!=1 taps only.
//
// launch_bounds (256,2): (256,4) forces a 64-VGPR cap and catastrophic
// accumulator spill (round-1: 7.3 GB HBM traffic, 2.8 ms).

#define WD   128
#define HWs  (128 * 128)
#define BD   5
#define CS   (BD * HWs)   // channel stride = 81920

__global__ __launch_bounds__(256, 2)
void TCA_49177375539279_kernel(const float* __restrict__ x,
                               const float* __restrict__ last,
                               const float* __restrict__ wq,
                               const float* __restrict__ wk,
                               const float* __restrict__ wv,
                               const float* __restrict__ wp,
                               float* __restrict__ out)
{
    const int z  = blockIdx.z;
    const int bi = z >> 3;          // batch 0..7
    const int hd = z & 7;           // head 0..7
    const int px = (blockIdx.x << 6) + (threadIdx.x & 63);   // 0..127 (per-lane)
    // py is identical across the 64 lanes of a wave -> force scalar so row
    // bounds checks become s_cbranch and base_dy is provably uniform.
    const int py = __builtin_amdgcn_readfirstlane((blockIdx.y << 2) + (threadIdx.x >> 6));

    const int ch0     = hd << 3;                    // input channel base (8 ch)
    const int base_in = (bi * 64 + ch0) * CS;       // uniform

    // per-lane clamped column offsets + 0/1 x-masks (xm[1] == 1 always)
    int xc[3]; float xm[3];
#pragma unroll
    for (int dx = 0; dx < 3; ++dx) {
        const int xx = px + dx - 1;
        xc[dx] = xx < 0 ? 0 : (xx > 127 ? 127 : xx);
        xm[dx] = ((unsigned)xx < 128u) ? 1.f : 0.f;
    }

    float q[4][BD], k[4][BD], v[4][BD];
#pragma unroll
    for (int c = 0; c < 4; ++c)
#pragma unroll
        for (int i = 0; i < BD; ++i) { q[c][i] = 0.f; k[c][i] = 0.f; v[c][i] = 0.f; }

    // weight bases for this head: (oc=4hd+c, j, dz, dy, dx) -> hd*216 + ...
    const float* __restrict__ wqb = wq + hd * 216;
    const float* __restrict__ wkb = wk + hd * 216;
    const float* __restrict__ wvb = wv + hd * 216;

    // ---------- pass 1: q = conv3x3x3(x, wq), 4 out-channels ----------
#pragma unroll 1
    for (int dy = 0; dy < 3; ++dy) {
        const int row = py + dy - 1;                 // SCALAR
        if ((unsigned)row < 128u) {                  // uniform branch
            const float* __restrict__ base_dy = x + (base_in + row * WD); // uniform
#pragma unroll
            for (int dx = 0; dx < 3; ++dx) {
                float xi[8][BD];
#pragma unroll
                for (int ic = 0; ic < 8; ++ic)
#pragma unroll
                    for (int d = 0; d < BD; ++d) {
                        float val = base_dy[ic * CS + d * HWs + xc[dx]]; // saddr + voffset
                        if (dx != 1) val *= xm[dx];                      // x-edge mask
                        xi[ic][d] = val;
                    }
#pragma unroll
                for (int c = 0; c < 4; ++c)
#pragma unroll
                    for (int j = 0; j < 2; ++j) {
                        const float* wr = wqb + (c * 2 + j) * 27 + dy * 3 + dx;
#pragma unroll
                        for (int dz = 0; dz < 3; ++dz) {
                            const float wgt = wr[dz * 9];
#pragma unroll
                            for (int i = 0; i < BD; ++i) {
                                const int d = i + dz - 1;      // compile-time
                                if (d >= 0 && d < BD)
                                    q[c][i] = fmaf(wgt, xi[c * 2 + j][d], q[c][i]);
                            }
                        }
                    }
            }
        }
    }

    // ---------- pass 2: k,v = conv3x3x3(last, wk/wv) ----------
#pragma unroll 1
    for (int dy = 0; dy < 3; ++dy) {
        const int row = py + dy - 1;                 // SCALAR
        if ((unsigned)row < 128u) {                  // uniform branch
            const float* __restrict__ base_dy = last + (base_in + row * WD); // uniform
#pragma unroll
            for (int dx = 0; dx < 3; ++dx) {
                float li[8][BD];
#pragma unroll
                for (int ic = 0; ic < 8; ++ic)
#pragma unroll
                    for (int d = 0; d < BD; ++d) {
                        float val = base_dy[ic * CS + d * HWs + xc[dx]];
                        if (dx != 1) val *= xm[dx];
                        li[ic][d] = val;
                    }
#pragma unroll
                for (int c = 0; c < 4; ++c)
#pragma unroll
                    for (int j = 0; j < 2; ++j) {
                        const float* wrk = wkb + (c * 2 + j) * 27 + dy * 3 + dx;
                        const float* wrv = wvb + (c * 2 + j) * 27 + dy * 3 + dx;
#pragma unroll
                        for (int dz = 0; dz < 3; ++dz) {
                            const float wk_ = wrk[dz * 9];
                            const float wv_ = wrv[dz * 9];
#pragma unroll
                            for (int i = 0; i < BD; ++i) {
                                const int d = i + dz - 1;
                                if (d >= 0 && d < BD) {
                                    k[c][i] = fmaf(wk_, li[c * 2 + j][d], k[c][i]);
                                    v[c][i] = fmaf(wv_, li[c * 2 + j][d], v[c][i]);
                                }
                            }
                        }
                    }
            }
        }
    }

    // ---------- attention: softmax_j( SCALE * q_i . k_j ) ----------
    const float SCALE = 0.35355339059327373f;   // 8^-0.5 (NUM_HEAD=8)
    float p[BD][BD];
#pragma unroll
    for (int i = 0; i < BD; ++i) {
        float s[BD];
        float m = -3.0e38f;
#pragma unroll
        for (int j = 0; j < BD; ++j) {
            float t = q[0][i] * k[0][j];
            t = fmaf(q[1][i], k[1][j], t);
            t = fmaf(q[2][i], k[2][j], t);
            t = fmaf(q[3][i], k[3][j], t);
            t *= SCALE;
            s[j] = t;
            m = fmaxf(m, t);
        }
        float sum = 0.f;
#pragma unroll
        for (int j = 0; j < BD; ++j) { float e = __expf(s[j] - m); p[i][j] = e; sum += e; }
        const float r = 1.0f / sum;
#pragma unroll
        for (int j = 0; j < BD; ++j) p[i][j] *= r;
    }

    // ---------- out = attn @ v, then 1x1 grouped proj (2 out per ch) ----------
    const int sp0 = py * WD + px;   // uniform row part + per-lane px -> saddr form
#pragma unroll
    for (int c = 0; c < 4; ++c) {
        const float w0 = wp[ch0 + 2 * c];
        const float w1 = wp[ch0 + 2 * c + 1];
#pragma unroll
        for (int i = 0; i < BD; ++i) {
            float o = p[i][0] * v[c][0];
            o = fmaf(p[i][1], v[c][1], o);
            o = fmaf(p[i][2], v[c][2], o);
            o = fmaf(p[i][3], v[c][3], o);
            o = fmaf(p[i][4], v[c][4], o);
            float* __restrict__ ob0 = out + (base_in + (2 * c)     * CS + i * HWs); // uniform
            float* __restrict__ ob1 = out + (base_in + (2 * c + 1) * CS + i * HWs); // uniform
            ob0[sp0] = w0 * o;
            ob1[sp0] = w1 * o;
        }
    }
}

extern "C" void kernel_launch(void* const* d_in, const int* in_sizes, int n_in,
                              void* d_out, int out_size, void* d_ws, size_t ws_size,
                              hipStream_t stream)
{
    const float* x    = (const float*)d_in[0];
    const float* last = (const float*)d_in[1];
    const float* wq   = (const float*)d_in[2];
    const float* wk   = (const float*)d_in[3];
    const float* wv   = (const float*)d_in[4];
    const float* wp   = (const float*)d_in[5];
    float* out = (float*)d_out;

    dim3 grid(2, 32, 64);   // (w tiles of 64, h tiles of 4, batch*heads)
    dim3 block(256);
    hipLaunchKernelGGL(TCA_49177375539279_kernel, grid, block, 0, stream,
                       x, last, wq, wk, wv, wp, out);
}

// Round 5
// 617.544 us; speedup vs baseline: 4.5887x; 1.1984x over previous
//
#include <hip/hip_runtime.h>

// Fused: grouped conv3x3x3 (q,k,v) -> per-location attention over depth B=5 ->
// grouped 1x1x1 proj. One thread handles one (batch, head, y, x).
//
// Scheduling-region discipline (rounds 1-4 post-mortem): the scheduler hoists
// independent loads across an entire unrolled region; spill magnitude tracks
// region size (whole pass unrolled -> 2.8 GB scratch; per-dy region (120
// loads) -> 300 MB; per-(dy,dx) region (40 loads) -> target 0). BOTH dy and
// dx loops are runtime ("#pragma unroll 1") so each region is one 3x3 column:
// 40 single-instruction loads + FMA block. Peak live set ~= 60 accumulators +
// 40 taps + ~12 misc < 128 VGPR.
//
// Addressing: py is wave-uniform (readfirstlane) -> row = py+dy-1 is SCALAR;
// OOB rows skipped by a uniform branch (exact: zero-padding contributes 0).
// Inside: base_dy = input + base_in + row*WD is a uniform SGPR base; per-load
// voffset = xcl + (ic*CS + d*HWs) is one v_add. X-edges: clamp + 0/1 mask mul
// (xm==1 for the center column; unconditional mul keeps indexing compile-time).
//
// launch_bounds (256,2): (256,4) forces a 64-VGPR cap -> catastrophic spill
// (round 1: 7.3 GB HBM traffic, 2.8 ms). Do not raise.

#define WD   128
#define HWs  (128 * 128)
#define BD   5
#define CS   (BD * HWs)   // channel stride = 81920

__global__ __launch_bounds__(256, 2)
void TCA_49177375539279_kernel(const float* __restrict__ x,
                               const float* __restrict__ last,
                               const float* __restrict__ wq,
                               const float* __restrict__ wk,
                               const float* __restrict__ wv,
                               const float* __restrict__ wp,
                               float* __restrict__ out)
{
    const int z  = blockIdx.z;
    const int bi = z >> 3;          // batch 0..7
    const int hd = z & 7;           // head 0..7
    const int px = (blockIdx.x << 6) + (threadIdx.x & 63);   // 0..127 (per-lane)
    // py is identical across the 64 lanes of a wave -> force scalar so row
    // bounds checks become s_cbranch and base_dy is provably uniform.
    const int py = __builtin_amdgcn_readfirstlane((blockIdx.y << 2) + (threadIdx.x >> 6));

    const int ch0     = hd << 3;                    // input channel base (8 ch)
    const int base_in = (bi * 64 + ch0) * CS;       // uniform

    float q[4][BD], k[4][BD], v[4][BD];
#pragma unroll
    for (int c = 0; c < 4; ++c)
#pragma unroll
        for (int i = 0; i < BD; ++i) { q[c][i] = 0.f; k[c][i] = 0.f; v[c][i] = 0.f; }

    // weight bases for this head: (oc=4hd+c, j, dz, dy, dx) -> hd*216 + ...
    const float* __restrict__ wqb = wq + hd * 216;
    const float* __restrict__ wkb = wk + hd * 216;
    const float* __restrict__ wvb = wv + hd * 216;

    // ---------- pass 1: q = conv3x3x3(x, wq), 4 out-channels ----------
#pragma unroll 1
    for (int dy = 0; dy < 3; ++dy) {
        const int row = py + dy - 1;                 // SCALAR
        if ((unsigned)row >= 128u) continue;         // uniform branch (exact)
        const float* __restrict__ base_dy = x + (base_in + row * WD); // uniform
#pragma unroll 1
        for (int dx = 0; dx < 3; ++dx) {             // runtime: 1 region per column
            const int xx  = px + dx - 1;
            const int xcl = xx < 0 ? 0 : (xx > 127 ? 127 : xx);
            const float xm = ((unsigned)xx < 128u) ? 1.f : 0.f;
            float xi[8][BD];
#pragma unroll
            for (int ic = 0; ic < 8; ++ic)
#pragma unroll
                for (int d = 0; d < BD; ++d)
                    xi[ic][d] = base_dy[ic * CS + d * HWs + xcl] * xm;
#pragma unroll
            for (int c = 0; c < 4; ++c)
#pragma unroll
                for (int j = 0; j < 2; ++j) {
                    const float* wr = wqb + (c * 2 + j) * 27 + dy * 3 + dx;
#pragma unroll
                    for (int dz = 0; dz < 3; ++dz) {
                        const float wgt = wr[dz * 9];
#pragma unroll
                        for (int i = 0; i < BD; ++i) {
                            const int d = i + dz - 1;      // compile-time
                            if (d >= 0 && d < BD)
                                q[c][i] = fmaf(wgt, xi[c * 2 + j][d], q[c][i]);
                        }
                    }
                }
        }
    }

    // ---------- pass 2: k,v = conv3x3x3(last, wk/wv) ----------
#pragma unroll 1
    for (int dy = 0; dy < 3; ++dy) {
        const int row = py + dy - 1;                 // SCALAR
        if ((unsigned)row >= 128u) continue;         // uniform branch (exact)
        const float* __restrict__ base_dy = last + (base_in + row * WD); // uniform
#pragma unroll 1
        for (int dx = 0; dx < 3; ++dx) {
            const int xx  = px + dx - 1;
            const int xcl = xx < 0 ? 0 : (xx > 127 ? 127 : xx);
            const float xm = ((unsigned)xx < 128u) ? 1.f : 0.f;
            float li[8][BD];
#pragma unroll
            for (int ic = 0; ic < 8; ++ic)
#pragma unroll
                for (int d = 0; d < BD; ++d)
                    li[ic][d] = base_dy[ic * CS + d * HWs + xcl] * xm;
#pragma unroll
            for (int c = 0; c < 4; ++c)
#pragma unroll
                for (int j = 0; j < 2; ++j) {
                    const float* wrk = wkb + (c * 2 + j) * 27 + dy * 3 + dx;
                    const float* wrv = wvb + (c * 2 + j) * 27 + dy * 3 + dx;
#pragma unroll
                    for (int dz = 0; dz < 3; ++dz) {
                        const float wk_ = wrk[dz * 9];
                        const float wv_ = wrv[dz * 9];
#pragma unroll
                        for (int i = 0; i < BD; ++i) {
                            const int d = i + dz - 1;
                            if (d >= 0 && d < BD) {
                                k[c][i] = fmaf(wk_, li[c * 2 + j][d], k[c][i]);
                                v[c][i] = fmaf(wv_, li[c * 2 + j][d], v[c][i]);
                            }
                        }
                    }
                }
        }
    }

    // ---------- attention: softmax_j( SCALE * q_i . k_j ) ----------
    const float SCALE = 0.35355339059327373f;   // 8^-0.5 (NUM_HEAD=8)
    float p[BD][BD];
#pragma unroll
    for (int i = 0; i < BD; ++i) {
        float s[BD];
        float m = -3.0e38f;
#pragma unroll
        for (int j = 0; j < BD; ++j) {
            float t = q[0][i] * k[0][j];
            t = fmaf(q[1][i], k[1][j], t);
            t = fmaf(q[2][i], k[2][j], t);
            t = fmaf(q[3][i], k[3][j], t);
            t *= SCALE;
            s[j] = t;
            m = fmaxf(m, t);
        }
        float sum = 0.f;
#pragma unroll
        for (int j = 0; j < BD; ++j) { float e = __expf(s[j] - m); p[i][j] = e; sum += e; }
        const float r = 1.0f / sum;
#pragma unroll
        for (int j = 0; j < BD; ++j) p[i][j] *= r;
    }

    // ---------- out = attn @ v, then 1x1 grouped proj (2 out per ch) ----------
    const int sp0 = py * WD + px;   // scalar row part + per-lane px
#pragma unroll
    for (int c = 0; c < 4; ++c) {
        const float w0 = wp[ch0 + 2 * c];
        const float w1 = wp[ch0 + 2 * c + 1];
#pragma unroll
        for (int i = 0; i < BD; ++i) {
            float o = p[i][0] * v[c][0];
            o = fmaf(p[i][1], v[c][1], o);
            o = fmaf(p[i][2], v[c][2], o);
            o = fmaf(p[i][3], v[c][3], o);
            o = fmaf(p[i][4], v[c][4], o);
            float* __restrict__ ob0 = out + (base_in + (2 * c)     * CS + i * HWs); // uniform
            float* __restrict__ ob1 = out + (base_in + (2 * c + 1) * CS + i * HWs); // uniform
            ob0[sp0] = w0 * o;
            ob1[sp0] = w1 * o;
        }
    }
}

extern "C" void kernel_launch(void* const* d_in, const int* in_sizes, int n_in,
                              void* d_out, int out_size, void* d_ws, size_t ws_size,
                              hipStream_t stream)
{
    const float* x    = (const float*)d_in[0];
    const float* last = (const float*)d_in[1];
    const float* wq   = (const float*)d_in[2];
    const float* wk   = (const float*)d_in[3];
    const float* wv   = (const float*)d_in[4];
    const float* wp   = (const float*)d_in[5];
    float* out = (float*)d_out;

    dim3 grid(2, 32, 64);   // (w tiles of 64, h tiles of 4, batch*heads)
    dim3 block(256);
    hipLaunchKernelGGL(TCA_49177375539279_kernel, grid, block, 0, stream,
                       x, last, wq, wk, wv, wp, out);
}